// Round 1
// baseline (67.385 us; speedup 1.0000x reference)
//
#include <hip/hip_runtime.h>

typedef __attribute__((ext_vector_type(8))) short short8;
typedef __attribute__((ext_vector_type(4))) float f32x4;

#define D128 128
#define LDS_STRIDE 136  // ushorts per LDS row: 128 + 8 pad -> 272 B, 16B-aligned, spreads banks

// fp32 -> bf16 round-to-nearest-even (bit pattern)
__device__ __forceinline__ unsigned short f2bf(float f) {
    unsigned int u = __float_as_uint(f);
    u += 0x7fffu + ((u >> 16) & 1u);
    return (unsigned short)(u >> 16);
}

__global__ __launch_bounds__(256)
void fused_linear_ln_kernel(const float* __restrict__ x,     // [N][128]
                            const float* __restrict__ w,     // [128 in][128 out] row-major
                            const float* __restrict__ bias,  // [128]
                            float* __restrict__ out)         // [N][128]
{
    __shared__ unsigned short wlds[D128 * LDS_STRIDE];  // transposed: wlds[col][k], bf16 bits

    const int tid = threadIdx.x;

    // ---- stage W (fp32 row-major [k][col]) into LDS as bf16 transposed [col][k] ----
    // 16384 floats = 4096 float4; 16 float4 per thread
    {
        const float4* w4 = (const float4*)w;
        #pragma unroll
        for (int it = 0; it < 16; ++it) {
            int idx = tid + it * 256;     // float4 index 0..4095
            int k   = idx >> 5;           // 32 float4 per k-row
            int c0  = (idx & 31) << 2;    // first col of this float4
            float4 v = w4[idx];
            wlds[(c0 + 0) * LDS_STRIDE + k] = f2bf(v.x);
            wlds[(c0 + 1) * LDS_STRIDE + k] = f2bf(v.y);
            wlds[(c0 + 2) * LDS_STRIDE + k] = f2bf(v.z);
            wlds[(c0 + 3) * LDS_STRIDE + k] = f2bf(v.w);
        }
    }
    __syncthreads();

    const int lane = tid & 63;
    const int wave = tid >> 6;
    const int lrow = lane & 15;   // fragment row (A) / col (B,D)
    const int lk   = lane >> 4;   // 0..3: k-subgroup

    const long row_base = (long)blockIdx.x * 128 + wave * 32;

    // bias for this lane's 8 col-fragments (L2-hot after first block)
    float bias_v[8];
    #pragma unroll
    for (int cf = 0; cf < 8; ++cf) bias_v[cf] = bias[cf * 16 + lrow];

    // ---- load A rows (fp32) and convert to bf16 fragments ----
    // A frag (i,kk): lane holds A[row_base + i*16 + lrow][kk*32 + lk*8 + j], j=0..7
    short8 afrag[2][4];
    #pragma unroll
    for (int i = 0; i < 2; ++i) {
        const float* rp = x + (row_base + i * 16 + lrow) * D128 + lk * 8;
        #pragma unroll
        for (int kk = 0; kk < 4; ++kk) {
            const float4* p = (const float4*)(rp + kk * 32);
            float4 v0 = p[0];
            float4 v1 = p[1];
            short8 a;
            a[0] = (short)f2bf(v0.x); a[1] = (short)f2bf(v0.y);
            a[2] = (short)f2bf(v0.z); a[3] = (short)f2bf(v0.w);
            a[4] = (short)f2bf(v1.x); a[5] = (short)f2bf(v1.y);
            a[6] = (short)f2bf(v1.z); a[7] = (short)f2bf(v1.w);
            afrag[i][kk] = a;
        }
    }

    // ---- MFMA main loop: acc[i][cf] over 4 k-steps ----
    f32x4 acc[2][8];
    #pragma unroll
    for (int i = 0; i < 2; ++i)
        #pragma unroll
        for (int cf = 0; cf < 8; ++cf) acc[i][cf] = (f32x4){0.f, 0.f, 0.f, 0.f};

    #pragma unroll
    for (int kk = 0; kk < 4; ++kk) {
        short8 bfrag[8];
        #pragma unroll
        for (int cf = 0; cf < 8; ++cf) {
            int col = cf * 16 + lrow;
            const unsigned short* p = &wlds[col * LDS_STRIDE + kk * 32 + lk * 8];
            bfrag[cf] = *(const short8*)p;   // 16B aligned ds_read_b128
        }
        #pragma unroll
        for (int i = 0; i < 2; ++i)
            #pragma unroll
            for (int cf = 0; cf < 8; ++cf)
                acc[i][cf] = __builtin_amdgcn_mfma_f32_16x16x32_bf16(
                    afrag[i][kk], bfrag[cf], acc[i][cf], 0, 0, 0);
    }

    // ---- epilogue: + bias, per-row layernorm, store ----
    // D layout: col = lane&15 (lrow), row_in_16 = lk*4 + r
    #pragma unroll
    for (int i = 0; i < 2; ++i) {
        #pragma unroll
        for (int cf = 0; cf < 8; ++cf)
            #pragma unroll
            for (int r = 0; r < 4; ++r) acc[i][cf][r] += bias_v[cf];

        #pragma unroll
        for (int r = 0; r < 4; ++r) {
            float s = 0.f, q = 0.f;
            #pragma unroll
            for (int cf = 0; cf < 8; ++cf) {
                float z = acc[i][cf][r];
                s += z;
                q += z * z;
            }
            // reduce across the 16 lanes sharing this row (xor on low 4 bits)
            #pragma unroll
            for (int m = 1; m <= 8; m <<= 1) {
                s += __shfl_xor(s, m, 64);
                q += __shfl_xor(q, m, 64);
            }
            float mean = s * (1.0f / 128.0f);
            float var  = q * (1.0f / 128.0f) - mean * mean;
            float rs   = rsqrtf(var + 1e-5f);

            long row = row_base + i * 16 + lk * 4 + r;
            float* op = out + row * D128 + lrow;
            #pragma unroll
            for (int cf = 0; cf < 8; ++cf)
                op[cf * 16] = (acc[i][cf][r] - mean) * rs;
        }
    }
}

extern "C" void kernel_launch(void* const* d_in, const int* in_sizes, int n_in,
                              void* d_out, int out_size, void* d_ws, size_t ws_size,
                              hipStream_t stream) {
    const float* x    = (const float*)d_in[0];
    const float* w    = (const float*)d_in[1];
    const float* bias = (const float*)d_in[2];
    float* out        = (float*)d_out;

    int nrows = in_sizes[0] / D128;       // 262144
    int grid  = nrows / D128;             // 2048 blocks x 128 rows
    hipLaunchKernelGGL(fused_linear_ln_kernel, dim3(grid), dim3(256), 0, stream,
                       x, w, bias, out);
}

// Round 2
// 60.215 us; speedup vs baseline: 1.1191x; 1.1191x over previous
//
#include <hip/hip_runtime.h>

typedef __attribute__((ext_vector_type(8))) short short8;
typedef __attribute__((ext_vector_type(4))) float f32x4;

#define D128 128
#define LDS_STRIDE 136

// fp32 -> bf16 round-to-nearest-even (bit pattern)
__device__ __forceinline__ unsigned short f2bf(float f) {
    unsigned int u = __float_as_uint(f);
    u += 0x7fffu + ((u >> 16) & 1u);
    return (unsigned short)(u >> 16);
}

// ---------------------------------------------------------------------------
// Pre-kernel: convert W (fp32 [k=128][col=128]) into bf16 B-fragments in ws.
// Layout: fragment f = cf*4+kk (cf=0..7, kk=0..3); lane l=0..63 holds 8 bf16
// at ws[ (f*64 + l) * 8 .. +8 ] = B[k = kk*32 + (l>>4)*8 + j][col = cf*16 + (l&15)]
// Main kernel then loads each fragment as one fully-coalesced 1KB dwordx4 wave-load.
// ---------------------------------------------------------------------------
__global__ __launch_bounds__(256)
void convert_w_kernel(const float* __restrict__ w, unsigned short* __restrict__ wsb) {
    int t = blockIdx.x * 256 + threadIdx.x;   // 0..2047
    int f = t >> 6;
    int l = t & 63;
    int cf = f >> 2, kk = f & 3;
    int col   = cf * 16 + (l & 15);
    int kbase = kk * 32 + (l >> 4) * 8;
    short8 v;
    #pragma unroll
    for (int j = 0; j < 8; ++j)
        v[j] = (short)f2bf(w[(kbase + j) * D128 + col]);
    *(short8*)(wsb + (size_t)t * 8) = v;
}

// ---------------------------------------------------------------------------
// Main kernel: no LDS. Each block = 4 waves x 32 rows = 128 rows.
// B fragments come from ws (bf16, fragment-ordered, L1/L2-hot).
// ---------------------------------------------------------------------------
__global__ __launch_bounds__(256)
void fused_linear_ln_kernel(const float* __restrict__ x,
                            const unsigned short* __restrict__ wsb,
                            const float* __restrict__ bias,
                            float* __restrict__ out)
{
    const int tid  = threadIdx.x;
    const int lane = tid & 63;
    const int wave = tid >> 6;
    const int lrow = lane & 15;
    const int lk   = lane >> 4;

    const long row_base = (long)blockIdx.x * 128 + wave * 32;

    float bias_v[8];
    #pragma unroll
    for (int cf = 0; cf < 8; ++cf) bias_v[cf] = bias[cf * 16 + lrow];

    // ---- load A rows (fp32) and convert to bf16 fragments ----
    short8 afrag[2][4];
    #pragma unroll
    for (int i = 0; i < 2; ++i) {
        const float* rp = x + (row_base + i * 16 + lrow) * D128 + lk * 8;
        #pragma unroll
        for (int kk = 0; kk < 4; ++kk) {
            const float4* p = (const float4*)(rp + kk * 32);
            float4 v0 = p[0];
            float4 v1 = p[1];
            short8 a;
            a[0] = (short)f2bf(v0.x); a[1] = (short)f2bf(v0.y);
            a[2] = (short)f2bf(v0.z); a[3] = (short)f2bf(v0.w);
            a[4] = (short)f2bf(v1.x); a[5] = (short)f2bf(v1.y);
            a[6] = (short)f2bf(v1.z); a[7] = (short)f2bf(v1.w);
            afrag[i][kk] = a;
        }
    }

    // ---- MFMA main loop ----
    f32x4 acc[2][8];
    #pragma unroll
    for (int i = 0; i < 2; ++i)
        #pragma unroll
        for (int cf = 0; cf < 8; ++cf) acc[i][cf] = (f32x4){0.f, 0.f, 0.f, 0.f};

    #pragma unroll
    for (int kk = 0; kk < 4; ++kk) {
        short8 bfrag[8];
        #pragma unroll
        for (int cf = 0; cf < 8; ++cf)
            bfrag[cf] = *(const short8*)(wsb + (size_t)((cf * 4 + kk) * 64 + lane) * 8);
        #pragma unroll
        for (int i = 0; i < 2; ++i)
            #pragma unroll
            for (int cf = 0; cf < 8; ++cf)
                acc[i][cf] = __builtin_amdgcn_mfma_f32_16x16x32_bf16(
                    afrag[i][kk], bfrag[cf], acc[i][cf], 0, 0, 0);
    }

    // ---- epilogue: + bias, per-row layernorm, store ----
    #pragma unroll
    for (int i = 0; i < 2; ++i) {
        #pragma unroll
        for (int cf = 0; cf < 8; ++cf)
            #pragma unroll
            for (int r = 0; r < 4; ++r) acc[i][cf][r] += bias_v[cf];

        #pragma unroll
        for (int r = 0; r < 4; ++r) {
            float s = 0.f, q = 0.f;
            #pragma unroll
            for (int cf = 0; cf < 8; ++cf) {
                float z = acc[i][cf][r];
                s += z;
                q += z * z;
            }
            #pragma unroll
            for (int m = 1; m <= 8; m <<= 1) {
                s += __shfl_xor(s, m, 64);
                q += __shfl_xor(q, m, 64);
            }
            float mean = s * (1.0f / 128.0f);
            float var  = q * (1.0f / 128.0f) - mean * mean;
            float rs   = rsqrtf(var + 1e-5f);

            long row = row_base + i * 16 + lk * 4 + r;
            float* op = out + row * D128 + lrow;
            #pragma unroll
            for (int cf = 0; cf < 8; ++cf)
                op[cf * 16] = (acc[i][cf][r] - mean) * rs;
        }
    }
}

// ---------------------------------------------------------------------------
// Fallback (ws too small): previous LDS-staged version, known-correct.
// ---------------------------------------------------------------------------
__global__ __launch_bounds__(256)
void fused_linear_ln_lds_kernel(const float* __restrict__ x,
                                const float* __restrict__ w,
                                const float* __restrict__ bias,
                                float* __restrict__ out)
{
    __shared__ unsigned short wlds[D128 * LDS_STRIDE];
    const int tid = threadIdx.x;
    {
        const float4* w4 = (const float4*)w;
        #pragma unroll
        for (int it = 0; it < 16; ++it) {
            int idx = tid + it * 256;
            int k   = idx >> 5;
            int c0  = (idx & 31) << 2;
            float4 v = w4[idx];
            wlds[(c0 + 0) * LDS_STRIDE + k] = f2bf(v.x);
            wlds[(c0 + 1) * LDS_STRIDE + k] = f2bf(v.y);
            wlds[(c0 + 2) * LDS_STRIDE + k] = f2bf(v.z);
            wlds[(c0 + 3) * LDS_STRIDE + k] = f2bf(v.w);
        }
    }
    __syncthreads();

    const int lane = tid & 63;
    const int wave = tid >> 6;
    const int lrow = lane & 15;
    const int lk   = lane >> 4;
    const long row_base = (long)blockIdx.x * 128 + wave * 32;

    float bias_v[8];
    #pragma unroll
    for (int cf = 0; cf < 8; ++cf) bias_v[cf] = bias[cf * 16 + lrow];

    short8 afrag[2][4];
    #pragma unroll
    for (int i = 0; i < 2; ++i) {
        const float* rp = x + (row_base + i * 16 + lrow) * D128 + lk * 8;
        #pragma unroll
        for (int kk = 0; kk < 4; ++kk) {
            const float4* p = (const float4*)(rp + kk * 32);
            float4 v0 = p[0];
            float4 v1 = p[1];
            short8 a;
            a[0] = (short)f2bf(v0.x); a[1] = (short)f2bf(v0.y);
            a[2] = (short)f2bf(v0.z); a[3] = (short)f2bf(v0.w);
            a[4] = (short)f2bf(v1.x); a[5] = (short)f2bf(v1.y);
            a[6] = (short)f2bf(v1.z); a[7] = (short)f2bf(v1.w);
            afrag[i][kk] = a;
        }
    }

    f32x4 acc[2][8];
    #pragma unroll
    for (int i = 0; i < 2; ++i)
        #pragma unroll
        for (int cf = 0; cf < 8; ++cf) acc[i][cf] = (f32x4){0.f, 0.f, 0.f, 0.f};

    #pragma unroll
    for (int kk = 0; kk < 4; ++kk) {
        short8 bfrag[8];
        #pragma unroll
        for (int cf = 0; cf < 8; ++cf) {
            int col = cf * 16 + lrow;
            bfrag[cf] = *(const short8*)&wlds[col * LDS_STRIDE + kk * 32 + lk * 8];
        }
        #pragma unroll
        for (int i = 0; i < 2; ++i)
            #pragma unroll
            for (int cf = 0; cf < 8; ++cf)
                acc[i][cf] = __builtin_amdgcn_mfma_f32_16x16x32_bf16(
                    afrag[i][kk], bfrag[cf], acc[i][cf], 0, 0, 0);
    }

    #pragma unroll
    for (int i = 0; i < 2; ++i) {
        #pragma unroll
        for (int cf = 0; cf < 8; ++cf)
            #pragma unroll
            for (int r = 0; r < 4; ++r) acc[i][cf][r] += bias_v[cf];

        #pragma unroll
        for (int r = 0; r < 4; ++r) {
            float s = 0.f, q = 0.f;
            #pragma unroll
            for (int cf = 0; cf < 8; ++cf) {
                float z = acc[i][cf][r];
                s += z; q += z * z;
            }
            #pragma unroll
            for (int m = 1; m <= 8; m <<= 1) {
                s += __shfl_xor(s, m, 64);
                q += __shfl_xor(q, m, 64);
            }
            float mean = s * (1.0f / 128.0f);
            float var  = q * (1.0f / 128.0f) - mean * mean;
            float rs   = rsqrtf(var + 1e-5f);
            long row = row_base + i * 16 + lk * 4 + r;
            float* op = out + row * D128 + lrow;
            #pragma unroll
            for (int cf = 0; cf < 8; ++cf)
                op[cf * 16] = (acc[i][cf][r] - mean) * rs;
        }
    }
}

extern "C" void kernel_launch(void* const* d_in, const int* in_sizes, int n_in,
                              void* d_out, int out_size, void* d_ws, size_t ws_size,
                              hipStream_t stream) {
    const float* x    = (const float*)d_in[0];
    const float* w    = (const float*)d_in[1];
    const float* bias = (const float*)d_in[2];
    float* out        = (float*)d_out;

    int nrows = in_sizes[0] / D128;
    int grid  = nrows / D128;

    if (ws_size >= 32 * 1024) {
        unsigned short* wsb = (unsigned short*)d_ws;
        hipLaunchKernelGGL(convert_w_kernel, dim3(8), dim3(256), 0, stream, w, wsb);
        hipLaunchKernelGGL(fused_linear_ln_kernel, dim3(grid), dim3(256), 0, stream,
                           x, wsb, bias, out);
    } else {
        hipLaunchKernelGGL(fused_linear_ln_lds_kernel, dim3(grid), dim3(256), 0, stream,
                           x, w, bias, out);
    }
}